// Round 4
// baseline (444.029 us; speedup 1.0000x reference)
//
#include <hip/hip_runtime.h>
#include <cstdint>
#include <cstddef>

#define N_    16
#define DIM_  2048
#define RF_   256
#define PN_   64
#define TOPK_ 10
#define HW_   128
#define KFULL (DIM_*HW_)   /* 262144 */
#define KMV   (TOPK_*RF_)  /* 2560 */

#define AS1 __attribute__((address_space(1)))
#define AS3 __attribute__((address_space(3)))

typedef __attribute__((ext_vector_type(8))) short bf16x8;
typedef __attribute__((ext_vector_type(4))) float f32x4;
typedef __attribute__((ext_vector_type(8))) unsigned short u16x8;

__device__ __forceinline__ unsigned short f2bf(float f) {
  unsigned u = __builtin_bit_cast(unsigned, f);
  unsigned r = (u + 0x7FFFu + ((u >> 16) & 1u)) >> 16;
  return (unsigned short)r;
}

// ---------------------------------------------------------------------------
// Weight convert fp32 [O][C] -> bf16 k-quad-major W'[C/8][O][8], LDS-tiled so
// BOTH sides are coalesced (r3 version scattered writes at O*16B stride ->
// WRITE_SIZE 56MB vs 28MB ideal, 45us). Tile = 64 o x 32 cg cells (16B/cell).
// Read: 32 consecutive threads = 1KB contiguous along C. Write: 64
// consecutive threads = 1KB contiguous along O. Also zero-inits dsum+flags.
// Grid: 864 tiles (32 + 320 + 256 + 256).
// ---------------------------------------------------------------------------
__global__ __launch_bounds__(256)
void cvt_all_kernel(const float* __restrict__ s0, const float* __restrict__ s1,
                    const float* __restrict__ s2, const float* __restrict__ s3,
                    unsigned short* __restrict__ d0, unsigned short* __restrict__ d1,
                    unsigned short* __restrict__ d2, unsigned short* __restrict__ d3,
                    float* __restrict__ dsum) {
  __shared__ u16x8 tile[32][65];   // [cg_local][o_local], +1 cell pad
  const int t = threadIdx.x;
  int gid = blockIdx.x * 256 + t;
  if (gid < 1152) dsum[gid] = 0.f;   // dsum (1088) + flags (64), contiguous

  int bid = blockIdx.x;
  const float* s; unsigned short* d; int O, CG, tb;
  if (bid < 32)       { s = s0; d = d0; O = RF_;  CG = DIM_ / 8; tb = bid; }
  else if (bid < 352) { s = s1; d = d1; O = DIM_; CG = KMV  / 8; tb = bid - 32; }
  else if (bid < 608) { s = s2; d = d2; O = DIM_; CG = DIM_ / 8; tb = bid - 352; }
  else                { s = s3; d = d3; O = DIM_; CG = DIM_ / 8; tb = bid - 608; }
  const int nCgT = CG / 32;
  const int o0  = (tb / nCgT) * 64;
  const int cg0 = (tb % nCgT) * 32;
  const size_t C = (size_t)CG * 8;

  // read + convert: idx = i*256+t -> o_l = idx>>5, cg_l = idx&31
#pragma unroll
  for (int i = 0; i < 8; ++i) {
    int idx = i * 256 + t, ol = idx >> 5, cg = idx & 31;
    const float* sp = s + (size_t)(o0 + ol) * C + (size_t)(cg0 + cg) * 8;
    float4 a = *(const float4*)sp;
    float4 b = *(const float4*)(sp + 4);
    u16x8 pk;
    pk[0] = f2bf(a.x); pk[1] = f2bf(a.y); pk[2] = f2bf(a.z); pk[3] = f2bf(a.w);
    pk[4] = f2bf(b.x); pk[5] = f2bf(b.y); pk[6] = f2bf(b.z); pk[7] = f2bf(b.w);
    tile[cg][ol] = pk;
  }
  __syncthreads();
  // write: idx -> cg_l = idx>>6, o_l = idx&63
#pragma unroll
  for (int i = 0; i < 8; ++i) {
    int idx = i * 256 + t, cg = idx >> 6, ol = idx & 63;
    *(u16x8*)(d + (size_t)(cg0 + cg) * ((size_t)O * 8) + (size_t)(o0 + ol) * 8) =
        tile[cg][ol];
  }
}

// ---------------------------------------------------------------------------
// proto [64][2048][128] fp32 -> protoT' [64][kq=256][s=128][8] bf16
// (k-quad-major). Also FUSES the ||p||^2 partial (moved out of dist_partial):
// each block sums squares of the 32x128 chunk it already reads, one atomic
// per wave into dsum[1024+p].
// ---------------------------------------------------------------------------
__global__ __launch_bounds__(256)
void transpose_proto_kernel(const float* __restrict__ src,
                            unsigned short* __restrict__ dst,
                            float* __restrict__ dsum) {
  __shared__ float tile[32][129];
  const int p = blockIdx.x;
  const int c0 = blockIdx.y * 32;
  const int t = threadIdx.x;
  const float* sp = src + ((size_t)p * DIM_ + c0) * HW_;
  float sq = 0.f;
#pragma unroll
  for (int i = 0; i < 4; ++i) {
    int g = i * 256 + t;
    int ci = g >> 5, s4 = g & 31;
    float4 v = *(const float4*)(sp + (size_t)ci * HW_ + s4 * 4);
    sq += v.x * v.x + v.y * v.y + v.z * v.z + v.w * v.w;
    int sb = s4 * 4;
    tile[ci][sb] = v.x; tile[ci][sb + 1] = v.y; tile[ci][sb + 2] = v.z; tile[ci][sb + 3] = v.w;
  }
#pragma unroll
  for (int m = 1; m < 64; m <<= 1) sq += __shfl_xor(sq, m, 64);
  if ((t & 63) == 0) atomicAdd(&dsum[1024 + p], sq);
  __syncthreads();
  // 4 kq-groups x 128 s = 512 cells of 16B; 2 cells per thread.
  unsigned short* dp = dst + (size_t)p * HW_ * DIM_ + (size_t)(c0 >> 3) * 1024;
#pragma unroll
  for (int i = 0; i < 2; ++i) {
    int cidx = i * 256 + t;
    int kg = cidx >> 7, s = cidx & 127;
    u16x8 pk;
#pragma unroll
    for (int u = 0; u < 8; ++u) pk[u] = f2bf(tile[kg * 8 + u][s]);
    *(u16x8*)(dp + (size_t)kg * 1024 + (size_t)s * 8) = pk;
  }
}

// ---------------------------------------------------------------------------
// dist partials, T14 async-stage pipeline (r4 rewrite). 512 blocks, each owns
// a 512-float k-chunk processed in 8 phases of 64. Phase i+1's global loads
// go to REGISTERS before compute(i); ds_write after compute; ONE barrier per
// phase. Old version exposed a full HBM round trip per phase behind a
// vmcnt(0)-draining __syncthreads (46us vs ~15us floor). ||p||^2 moved to
// transpose_proto. LDS 2x(16+64)x68 floats = 42.5KB -> 3 blocks/CU.
// ---------------------------------------------------------------------------
__global__ __launch_bounds__(256)
void dist_partial_kernel(const float* __restrict__ x, const float* __restrict__ proto,
                         float* __restrict__ dsum) {
  __shared__ alignas(16) float xl[2][16][68];
  __shared__ alignas(16) float pl[2][64][68];
  const int t = threadIdx.x, b = blockIdx.x;
  const int n0 = t & 7, pb = t >> 3;          // compute mapping (pb in [0,32))
  const int xr = t >> 4, xc = (t & 15) * 4;   // x-stage mapping
  float acc[2][2] = {};
  const size_t kbase = (size_t)b * 512;

  float4 rx, rp[4];
  auto gload = [&](int ph) {
    const size_t k0 = kbase + ph * 64;
    rx = *(const float4*)(x + (size_t)xr * KFULL + k0 + xc);
#pragma unroll
    for (int i = 0; i < 4; ++i) {
      int idx = i * 256 + t;
      rp[i] = *(const float4*)(proto + (size_t)(idx >> 4) * KFULL + k0 + (idx & 15) * 4);
    }
  };
  auto swrite = [&](int buf) {
    *(float4*)&xl[buf][xr][xc] = rx;
#pragma unroll
    for (int i = 0; i < 4; ++i) {
      int idx = i * 256 + t;
      *(float4*)&pl[buf][idx >> 4][(idx & 15) * 4] = rp[i];
    }
  };

  gload(0); swrite(0);
  __syncthreads();
  for (int ph = 0; ph < 8; ++ph) {
    const int buf = ph & 1;
    if (ph + 1 < 8) gload(ph + 1);   // in flight across compute(ph)
#pragma unroll 8
    for (int k = 0; k < 64; k += 4) {
      float4 xa = *(float4*)&xl[buf][n0][k];
      float4 xb = *(float4*)&xl[buf][n0 + 8][k];
      float4 p0 = *(float4*)&pl[buf][pb][k];
      float4 p1 = *(float4*)&pl[buf][pb + 32][k];
      acc[0][0] += xa.x*p0.x + xa.y*p0.y + xa.z*p0.z + xa.w*p0.w;
      acc[0][1] += xa.x*p1.x + xa.y*p1.y + xa.z*p1.z + xa.w*p1.w;
      acc[1][0] += xb.x*p0.x + xb.y*p0.y + xb.z*p0.z + xb.w*p0.w;
      acc[1][1] += xb.x*p1.x + xb.y*p1.y + xb.z*p1.z + xb.w*p1.w;
    }
    // swrite into buf^1: all waves passed compute(ph-1) on buf^1 at the
    // barrier that opened this phase -> safe. One barrier per phase.
    if (ph + 1 < 8) swrite(buf ^ 1);
    __syncthreads();
  }

  atomicAdd(&dsum[n0 * 64 + pb],          -2.f * acc[0][0]);
  atomicAdd(&dsum[n0 * 64 + pb + 32],     -2.f * acc[0][1]);
  atomicAdd(&dsum[(n0 + 8) * 64 + pb],    -2.f * acc[1][0]);
  atomicAdd(&dsum[(n0 + 8) * 64 + pb + 32], -2.f * acc[1][1]);
}

// ---------------------------------------------------------------------------
// select: rank-based, fully parallel. Block n (16 blocks x 64 lanes): lane p
// ranks its dist among all 64 (stable argsort order); rank<10 -> idx[n][rank].
// flags[] pre-zeroed by cvt_all; benign same-value race across blocks.
// ---------------------------------------------------------------------------
__global__ __launch_bounds__(64)
void select_kernel(const float* __restrict__ dsum, int* __restrict__ idx,
                   int* __restrict__ flags) {
  __shared__ float sh[64];
  const int n = blockIdx.x, t = threadIdx.x;
  float dval = dsum[1024 + t] + dsum[n * 64 + t];
  sh[t] = dval;
  __syncthreads();
  int rank = 0;
#pragma unroll
  for (int j = 0; j < 64; ++j) {
    float o = sh[j];
    rank += (o < dval || (o == dval && j < t)) ? 1 : 0;
  }
  if (rank < TOPK_) { idx[n * TOPK_ + rank] = t; flags[t] = 1; }
}

// ---------------------------------------------------------------------------
// bf16 MFMA GEMM, tile 64Mx128Nx64K, 128 threads = 2 waves, wave-tile 64x64
// = 4x4 of 16x16x32. Triple-buffered LDS, 2-deep prefetch, counted vmcnt
// (stage-(it+1) loads stay in flight across the raw s_barrier).
// All staged tensors k-quad-major (W'[kq][O][8], X'[batch][kq][s][8]):
// every global_load_lds reads ONE contiguous 1KB run. Unchanged from r3
// (dropped out of top-5 at ~<45us; awaiting fresh counters).
// ---------------------------------------------------------------------------
#define BM 64
#define BKK 64

template <int MODE>
__global__ __launch_bounds__(128, 2)
void mfma_gemm_kernel(const unsigned short* __restrict__ Wb,
                      const unsigned short* __restrict__ Xb,
                      void* __restrict__ OutP,
                      const float* __restrict__ inputs,
                      const int* __restrict__ idxp,
                      const int* __restrict__ flags,
                      int K, int O, int Ldim) {
  __shared__ alignas(16) unsigned short Al[3][8 * BM * 8];    // 3 x 8 KB
  __shared__ alignas(16) unsigned short Bl[3][8 * 128 * 8];   // 3 x 16 KB

  const int t = threadIdx.x;
  const int w = t >> 6;          // wave 0/1 -> n-half
  const int lane = t & 63;
  const int q = lane >> 4;
  const int l15 = lane & 15;
  const int batch = blockIdx.y;
  const int o0 = blockIdx.x * BM;

  if (MODE == 0 && flags && !flags[batch]) return;

  int idreg = 0;
  if (MODE == 1 && lane < TOPK_) idreg = idxp[batch * TOPK_ + lane];

  f32x4 acc[4][4] = {};

  auto issue = [&](int k0, int buf) {
    // A: wave w stages k-quads 4w..4w+3; each load = contiguous 1KB of
    // W'[kq][O][8] starting at output-row o0 (lane*16B appended by HW).
#pragma unroll
    for (int i = 0; i < 4; ++i) {
      int qk = w * 4 + i;
      const unsigned short* ga =
          Wb + (size_t)((k0 >> 3) + qk) * (O * 8) + (size_t)(o0 + lane) * 8;
      __builtin_amdgcn_global_load_lds((const AS1 void*)ga,
                                       (AS3 void*)(&Al[buf][qk * 512]), 16, 0, 0);
    }
    const unsigned short* base;
    if (MODE == 1) {
      int id = __shfl(idreg, k0 >> 8, 64);
      base = Xb + (size_t)id * (HW_ * RF_) + (size_t)((k0 & 255) >> 3) * 1024;
    } else {
      base = Xb + (size_t)batch * HW_ * K + (size_t)(k0 >> 3) * 1024;
    }
    // B: wave w stages 8 of 16 (qk, half) 1KB regions of X'[kq][s][8].
#pragma unroll
    for (int i = 0; i < 8; ++i) {
      int v = w * 8 + i;
      int qk = v >> 1, h = v & 1;
      const unsigned short* gb = base + (size_t)qk * 1024 + (size_t)(h * 64 + lane) * 8;
      __builtin_amdgcn_global_load_lds((const AS1 void*)gb,
                                       (AS3 void*)(&Bl[buf][qk * 1024 + h * 512]), 16, 0, 0);
    }
  };

  const int nIter = K / BKK;   // 32 (MODE 0/2/3) or 40 (MODE 1)

  issue(0, 0);
  issue(BKK, 1);               // 24 loads/wave outstanding

  for (int it = 0; it < nIter; ++it) {
    const int buf = it % 3;
    // Counted wait: stage-it loads (oldest 12) landed; stage-(it+1) loads
    // stay in flight across the barrier. Full drain only on the last iter.
    if (it + 1 < nIter) {
      asm volatile("s_waitcnt vmcnt(12)" ::: "memory");
    } else {
      asm volatile("s_waitcnt vmcnt(0)" ::: "memory");
    }
    __builtin_amdgcn_s_barrier();
#pragma unroll
    for (int s = 0; s < 2; ++s) {
      bf16x8 af[4], bfr[4];
#pragma unroll
      for (int mt = 0; mt < 4; ++mt)
        af[mt] = *(const bf16x8*)(&Al[buf][(s * 4 + q) * 512 + (mt * 16 + l15) * 8]);
#pragma unroll
      for (int nt = 0; nt < 4; ++nt)
        bfr[nt] = *(const bf16x8*)(&Bl[buf][(s * 4 + q) * 1024 + (w * 64 + nt * 16 + l15) * 8]);
#pragma unroll
      for (int mt = 0; mt < 4; ++mt)
#pragma unroll
        for (int nt = 0; nt < 4; ++nt)
          acc[mt][nt] = __builtin_amdgcn_mfma_f32_16x16x32_bf16(af[mt], bfr[nt], acc[mt][nt], 0, 0, 0);
    }
    if (it + 2 < nIter) issue((it + 2) * BKK, (it + 2) % 3);
  }

  // ---------------- epilogue ----------------
  const float CAL = 1.0f - 1.0f / 262144.0f;

  // MODE2 scratch aliases Al buffer 0 (safe: last K-stage uses buffer 1).
  float* nsumS = (float*)&Al[0][0];         // [2][64]
  float* nsqS  = (float*)&Al[0][0] + 128;   // [2][64]

  if (MODE == 2) {
#pragma unroll
    for (int mt = 0; mt < 4; ++mt)
#pragma unroll
      for (int reg = 0; reg < 4; ++reg) {
        float s_ = 0.f, q_ = 0.f;
#pragma unroll
        for (int nt = 0; nt < 4; ++nt) {
          float v = acc[mt][nt][reg];
          s_ += v; q_ += v * v;
        }
#pragma unroll
        for (int m = 1; m < 16; m <<= 1) {
          s_ += __shfl_xor(s_, m, 64);
          q_ += __shfl_xor(q_, m, 64);
        }
        if (l15 == 0) {
          int ol = mt * 16 + q * 4 + reg;
          nsumS[w * 64 + ol] = s_; nsqS[w * 64 + ol] = q_;
        }
      }
    __syncthreads();
  }

  if (MODE == 3) {
    float* ofb = (float*)OutP + (size_t)batch * DIM_ * HW_;
    const float* inb = inputs + (size_t)batch * DIM_ * HW_;
#pragma unroll
    for (int mt = 0; mt < 4; ++mt)
#pragma unroll
      for (int nt = 0; nt < 4; ++nt) {
        int o = o0 + mt * 16 + q * 4;
        int s = w * 64 + nt * 16 + l15;
        f32x4 v = acc[mt][nt];
#pragma unroll
        for (int g = 0; g < 4; ++g) {
          float in = inb[(size_t)(o + g) * HW_ + s];
          float sg = 1.f / (1.f + expf(-v[g]));
          ofb[(size_t)(o + g) * HW_ + s] = in * (1.f + sg);
        }
      }
  } else {
    // Store to X'[batch][o/8][s][8] (k-quad-major): ushort4 at
    // (o>>3)*1024 + s*8 + (o&7); (o&7) in {0,4}. Contiguous 256B per
    // 16-lane group instead of a 64-line scatter.
    unsigned short* ob = (unsigned short*)OutP + (size_t)batch * HW_ * Ldim;
    const float* inb = (MODE == 1) ? inputs + (size_t)batch * DIM_ * HW_ : nullptr;
#pragma unroll
    for (int mt = 0; mt < 4; ++mt) {
      float mean[4], rs[4];
      if (MODE == 2) {
#pragma unroll
        for (int reg = 0; reg < 4; ++reg) {
          int ol = mt * 16 + q * 4 + reg;
          float ts = nsumS[ol] + nsumS[64 + ol];
          float tq = nsqS[ol] + nsqS[64 + ol];
          float mn = ts * (1.f / 128.f);
          float vr = tq * (1.f / 128.f) - mn * mn;
          mean[reg] = mn; rs[reg] = rsqrtf(vr + 1e-5f);
        }
      }
#pragma unroll
      for (int nt = 0; nt < 4; ++nt) {
        int o = o0 + mt * 16 + q * 4;
        int s = w * 64 + nt * 16 + l15;
        f32x4 v = acc[mt][nt];
        float r[4];
        if (MODE == 0) {
#pragma unroll
          for (int g = 0; g < 4; ++g) r[g] = v[g];
        } else if (MODE == 1) {
          const float* ip = inb + (size_t)o * HW_ + s;
#pragma unroll
          for (int g = 0; g < 4; ++g)
            r[g] = fmaxf(0.f, 0.5f * ip[(size_t)g * HW_] + CAL * v[g]);
        } else {
#pragma unroll
          for (int g = 0; g < 4; ++g) r[g] = (v[g] - mean[g]) * rs[g];
        }
        ushort4 pk;
        pk.x = f2bf(r[0]); pk.y = f2bf(r[1]); pk.z = f2bf(r[2]); pk.w = f2bf(r[3]);
        *(ushort4*)(ob + (size_t)(o >> 3) * 1024 + (size_t)s * 8 + (o & 7)) = pk;
      }
    }
  }
}

// ---------------------------------------------------------------------------
extern "C" void kernel_launch(void* const* d_in, const int* in_sizes, int n_in,
                              void* d_out, int out_size, void* d_ws, size_t ws_size,
                              hipStream_t stream) {
  const float* inputs = (const float*)d_in[0];
  const float* proto  = (const float*)d_in[1];
  const float* w_rf   = (const float*)d_in[2];
  const float* w_rfmv = (const float*)d_in[3];
  const float* w_rms  = (const float*)d_in[4];
  const float* w_fuse = (const float*)d_in[5];
  float* out = (float*)d_out;

  uint8_t* ws = (uint8_t*)d_ws;
  size_t off = 0;
  auto alloc = [&](size_t bytes) { uint8_t* p = ws + off; off += (bytes + 255) & ~(size_t)255; return p; };

  float* dsum  = (float*)alloc(1088 * 4);       // 4352 B (256-aligned size)
  int*   flags = (int*)alloc(PN_ * 4);          // contiguous after dsum -> zeroed together
  int*   idx   = (int*)alloc(N_ * TOPK_ * 4);
  unsigned short* wrf_b   = (unsigned short*)alloc((size_t)RF_ * DIM_ * 2);
  unsigned short* wrfmv_b = (unsigned short*)alloc((size_t)DIM_ * KMV * 2);
  unsigned short* wrms_b  = (unsigned short*)alloc((size_t)DIM_ * DIM_ * 2);
  unsigned short* wfuse_b = (unsigned short*)alloc((size_t)DIM_ * DIM_ * 2);
  unsigned short* xpT     = (unsigned short*)alloc((size_t)PN_ * HW_ * RF_ * 2);
  unsigned short* protoT  = (unsigned short*)alloc((size_t)PN_ * HW_ * DIM_ * 2);
  unsigned short* mvlT = protoT;                 // aliases (protoT dead after G1)
  unsigned short* mvaT = protoT + (size_t)N_ * HW_ * DIM_;

  cvt_all_kernel<<<864, 256, 0, stream>>>(w_rf, w_rfmv, w_rms, w_fuse,
                                          wrf_b, wrfmv_b, wrms_b, wfuse_b, dsum);
  transpose_proto_kernel<<<dim3(PN_, DIM_ / 32), 256, 0, stream>>>(proto, protoT, dsum);
  dist_partial_kernel<<<512, 256, 0, stream>>>(inputs, proto, dsum);
  select_kernel<<<N_, 64, 0, stream>>>(dsum, idx, flags);

  mfma_gemm_kernel<0><<<dim3(RF_ / BM, PN_), 128, 0, stream>>>(
      wrf_b, protoT, xpT, nullptr, nullptr, flags, DIM_, RF_, RF_);
  mfma_gemm_kernel<1><<<dim3(DIM_ / BM, N_), 128, 0, stream>>>(
      wrfmv_b, xpT, mvlT, inputs, idx, nullptr, KMV, DIM_, DIM_);
  mfma_gemm_kernel<2><<<dim3(DIM_ / BM, N_), 128, 0, stream>>>(
      wrms_b, mvlT, mvaT, nullptr, nullptr, nullptr, DIM_, DIM_, DIM_);
  mfma_gemm_kernel<3><<<dim3(DIM_ / BM, N_), 128, 0, stream>>>(
      wfuse_b, mvaT, out, inputs, nullptr, nullptr, DIM_, DIM_, DIM_);
}

// Round 5
// 372.088 us; speedup vs baseline: 1.1933x; 1.1933x over previous
//
#include <hip/hip_runtime.h>
#include <cstdint>
#include <cstddef>

#define N_    16
#define DIM_  2048
#define RF_   256
#define PN_   64
#define TOPK_ 10
#define HW_   128
#define KFULL (DIM_*HW_)   /* 262144 */
#define KMV   (TOPK_*RF_)  /* 2560 */

#define AS1 __attribute__((address_space(1)))
#define AS3 __attribute__((address_space(3)))

typedef __attribute__((ext_vector_type(8))) short bf16x8;
typedef __attribute__((ext_vector_type(4))) float f32x4;
typedef __attribute__((ext_vector_type(8))) unsigned short u16x8;

__device__ __forceinline__ unsigned short f2bf(float f) {
  unsigned u = __builtin_bit_cast(unsigned, f);
  unsigned r = (u + 0x7FFFu + ((u >> 16) & 1u)) >> 16;
  return (unsigned short)r;
}

// ---------------------------------------------------------------------------
// Weight convert fp32 [O][C] -> bf16 k-quad-major W'[C/8][O][8], LDS-tiled so
// BOTH sides are coalesced. Tile = 64 o x 32 cg cells (16B/cell).
// Read: 32 consecutive threads = 1KB contiguous along C. Write: 64
// consecutive threads = 1KB contiguous along O. Also zero-inits dsum+flags.
// Grid: 864 tiles (32 + 320 + 256 + 256).
// ---------------------------------------------------------------------------
__global__ __launch_bounds__(256)
void cvt_all_kernel(const float* __restrict__ s0, const float* __restrict__ s1,
                    const float* __restrict__ s2, const float* __restrict__ s3,
                    unsigned short* __restrict__ d0, unsigned short* __restrict__ d1,
                    unsigned short* __restrict__ d2, unsigned short* __restrict__ d3,
                    float* __restrict__ dsum) {
  __shared__ u16x8 tile[32][65];   // [cg_local][o_local], +1 cell pad
  const int t = threadIdx.x;
  int gid = blockIdx.x * 256 + t;
  if (gid < 1152) dsum[gid] = 0.f;   // dsum (1088) + flags (64), contiguous

  int bid = blockIdx.x;
  const float* s; unsigned short* d; int O, CG, tb;
  if (bid < 32)       { s = s0; d = d0; O = RF_;  CG = DIM_ / 8; tb = bid; }
  else if (bid < 352) { s = s1; d = d1; O = DIM_; CG = KMV  / 8; tb = bid - 32; }
  else if (bid < 608) { s = s2; d = d2; O = DIM_; CG = DIM_ / 8; tb = bid - 352; }
  else                { s = s3; d = d3; O = DIM_; CG = DIM_ / 8; tb = bid - 608; }
  const int nCgT = CG / 32;
  const int o0  = (tb / nCgT) * 64;
  const int cg0 = (tb % nCgT) * 32;
  const size_t C = (size_t)CG * 8;

  // read + convert: idx = i*256+t -> o_l = idx>>5, cg_l = idx&31
#pragma unroll
  for (int i = 0; i < 8; ++i) {
    int idx = i * 256 + t, ol = idx >> 5, cg = idx & 31;
    const float* sp = s + (size_t)(o0 + ol) * C + (size_t)(cg0 + cg) * 8;
    float4 a = *(const float4*)sp;
    float4 b = *(const float4*)(sp + 4);
    u16x8 pk;
    pk[0] = f2bf(a.x); pk[1] = f2bf(a.y); pk[2] = f2bf(a.z); pk[3] = f2bf(a.w);
    pk[4] = f2bf(b.x); pk[5] = f2bf(b.y); pk[6] = f2bf(b.z); pk[7] = f2bf(b.w);
    tile[cg][ol] = pk;
  }
  __syncthreads();
  // write: idx -> cg_l = idx>>6, o_l = idx&63
#pragma unroll
  for (int i = 0; i < 8; ++i) {
    int idx = i * 256 + t, cg = idx >> 6, ol = idx & 63;
    *(u16x8*)(d + (size_t)(cg0 + cg) * ((size_t)O * 8) + (size_t)(o0 + ol) * 8) =
        tile[cg][ol];
  }
}

// ---------------------------------------------------------------------------
// proto [64][2048][128] fp32 -> protoT' [64][kq=256][s=128][8] bf16
// (k-quad-major). ||p||^2 partial: r4's per-wave atomicAdd serialized 16384
// device atomics onto 2 cache lines (measured 105us, all pipes idle). Now:
// block-reduce then ONE PLAIN STORE per block into pnorm_part[cb][p];
// select_kernel sums the 64 partials. No atomics here at all.
// ---------------------------------------------------------------------------
__global__ __launch_bounds__(256)
void transpose_proto_kernel(const float* __restrict__ src,
                            unsigned short* __restrict__ dst,
                            float* __restrict__ pnorm_part) {
  __shared__ float tile[32][129];
  __shared__ float ssq[4];
  const int p = blockIdx.x;
  const int c0 = blockIdx.y * 32;
  const int t = threadIdx.x;
  const float* sp = src + ((size_t)p * DIM_ + c0) * HW_;
  float sq = 0.f;
#pragma unroll
  for (int i = 0; i < 4; ++i) {
    int g = i * 256 + t;
    int ci = g >> 5, s4 = g & 31;
    float4 v = *(const float4*)(sp + (size_t)ci * HW_ + s4 * 4);
    sq += v.x * v.x + v.y * v.y + v.z * v.z + v.w * v.w;
    int sb = s4 * 4;
    tile[ci][sb] = v.x; tile[ci][sb + 1] = v.y; tile[ci][sb + 2] = v.z; tile[ci][sb + 3] = v.w;
  }
#pragma unroll
  for (int m = 1; m < 64; m <<= 1) sq += __shfl_xor(sq, m, 64);
  if ((t & 63) == 0) ssq[t >> 6] = sq;
  __syncthreads();
  if (t == 0) pnorm_part[blockIdx.y * PN_ + p] = ssq[0] + ssq[1] + ssq[2] + ssq[3];
  // 4 kq-groups x 128 s = 512 cells of 16B; 2 cells per thread.
  unsigned short* dp = dst + (size_t)p * HW_ * DIM_ + (size_t)(c0 >> 3) * 1024;
#pragma unroll
  for (int i = 0; i < 2; ++i) {
    int cidx = i * 256 + t;
    int kg = cidx >> 7, s = cidx & 127;
    u16x8 pk;
#pragma unroll
    for (int u = 0; u < 8; ++u) pk[u] = f2bf(tile[kg * 8 + u][s]);
    *(u16x8*)(dp + (size_t)kg * 1024 + (size_t)s * 8) = pk;
  }
}

// ---------------------------------------------------------------------------
// dist partials, T14 async-stage pipeline. 512 blocks, each owns a 512-float
// k-chunk processed in 8 phases of 64. Phase i+1's global loads go to
// REGISTERS before compute(i); ds_write after compute; ONE barrier per
// phase. LDS 2x(16+64)x68 floats = 42.5KB -> 3 blocks/CU.
// ---------------------------------------------------------------------------
__global__ __launch_bounds__(256)
void dist_partial_kernel(const float* __restrict__ x, const float* __restrict__ proto,
                         float* __restrict__ dsum) {
  __shared__ alignas(16) float xl[2][16][68];
  __shared__ alignas(16) float pl[2][64][68];
  const int t = threadIdx.x, b = blockIdx.x;
  const int n0 = t & 7, pb = t >> 3;          // compute mapping (pb in [0,32))
  const int xr = t >> 4, xc = (t & 15) * 4;   // x-stage mapping
  float acc[2][2] = {};
  const size_t kbase = (size_t)b * 512;

  float4 rx, rp[4];
  auto gload = [&](int ph) {
    const size_t k0 = kbase + ph * 64;
    rx = *(const float4*)(x + (size_t)xr * KFULL + k0 + xc);
#pragma unroll
    for (int i = 0; i < 4; ++i) {
      int idx = i * 256 + t;
      rp[i] = *(const float4*)(proto + (size_t)(idx >> 4) * KFULL + k0 + (idx & 15) * 4);
    }
  };
  auto swrite = [&](int buf) {
    *(float4*)&xl[buf][xr][xc] = rx;
#pragma unroll
    for (int i = 0; i < 4; ++i) {
      int idx = i * 256 + t;
      *(float4*)&pl[buf][idx >> 4][(idx & 15) * 4] = rp[i];
    }
  };

  gload(0); swrite(0);
  __syncthreads();
  for (int ph = 0; ph < 8; ++ph) {
    const int buf = ph & 1;
    if (ph + 1 < 8) gload(ph + 1);   // in flight across compute(ph)
#pragma unroll 8
    for (int k = 0; k < 64; k += 4) {
      float4 xa = *(float4*)&xl[buf][n0][k];
      float4 xb = *(float4*)&xl[buf][n0 + 8][k];
      float4 p0 = *(float4*)&pl[buf][pb][k];
      float4 p1 = *(float4*)&pl[buf][pb + 32][k];
      acc[0][0] += xa.x*p0.x + xa.y*p0.y + xa.z*p0.z + xa.w*p0.w;
      acc[0][1] += xa.x*p1.x + xa.y*p1.y + xa.z*p1.z + xa.w*p1.w;
      acc[1][0] += xb.x*p0.x + xb.y*p0.y + xb.z*p0.z + xb.w*p0.w;
      acc[1][1] += xb.x*p1.x + xb.y*p1.y + xb.z*p1.z + xb.w*p1.w;
    }
    // swrite into buf^1: all waves passed compute(ph-1) on buf^1 at the
    // barrier that opened this phase -> safe. One barrier per phase.
    if (ph + 1 < 8) swrite(buf ^ 1);
    __syncthreads();
  }

  atomicAdd(&dsum[n0 * 64 + pb],          -2.f * acc[0][0]);
  atomicAdd(&dsum[n0 * 64 + pb + 32],     -2.f * acc[0][1]);
  atomicAdd(&dsum[(n0 + 8) * 64 + pb],    -2.f * acc[1][0]);
  atomicAdd(&dsum[(n0 + 8) * 64 + pb + 32], -2.f * acc[1][1]);
}

// ---------------------------------------------------------------------------
// select: rank-based, fully parallel. Block n (16 blocks x 64 lanes): lane p
// sums the 64 pnorm partials (coalesced 256B reads, L2-resident) + the -2xy
// term, ranks its dist among all 64 (stable argsort order); rank<10 ->
// idx[n][rank]. flags[] pre-zeroed by cvt_all; benign same-value race.
// ---------------------------------------------------------------------------
__global__ __launch_bounds__(64)
void select_kernel(const float* __restrict__ dsum, const float* __restrict__ pnorm_part,
                   int* __restrict__ idx, int* __restrict__ flags) {
  __shared__ float sh[64];
  const int n = blockIdx.x, t = threadIdx.x;
  float pn = 0.f;
#pragma unroll 8
  for (int cb = 0; cb < DIM_ / 32; ++cb) pn += pnorm_part[cb * PN_ + t];
  float dval = pn + dsum[n * 64 + t];
  sh[t] = dval;
  __syncthreads();
  int rank = 0;
#pragma unroll
  for (int j = 0; j < 64; ++j) {
    float o = sh[j];
    rank += (o < dval || (o == dval && j < t)) ? 1 : 0;
  }
  if (rank < TOPK_) { idx[n * TOPK_ + rank] = t; flags[t] = 1; }
}

// ---------------------------------------------------------------------------
// bf16 MFMA GEMM, tile 64Mx128Nx64K, 128 threads = 2 waves, wave-tile 64x64
// = 4x4 of 16x16x32. Triple-buffered LDS, 2-deep prefetch, counted vmcnt
// (stage-(it+1) loads stay in flight across the raw s_barrier).
// All staged tensors k-quad-major (W'[kq][O][8], X'[batch][kq][s][8]):
// every global_load_lds reads ONE contiguous 1KB run. Unchanged from r3.
// ---------------------------------------------------------------------------
#define BM 64
#define BKK 64

template <int MODE>
__global__ __launch_bounds__(128, 2)
void mfma_gemm_kernel(const unsigned short* __restrict__ Wb,
                      const unsigned short* __restrict__ Xb,
                      void* __restrict__ OutP,
                      const float* __restrict__ inputs,
                      const int* __restrict__ idxp,
                      const int* __restrict__ flags,
                      int K, int O, int Ldim) {
  __shared__ alignas(16) unsigned short Al[3][8 * BM * 8];    // 3 x 8 KB
  __shared__ alignas(16) unsigned short Bl[3][8 * 128 * 8];   // 3 x 16 KB

  const int t = threadIdx.x;
  const int w = t >> 6;          // wave 0/1 -> n-half
  const int lane = t & 63;
  const int q = lane >> 4;
  const int l15 = lane & 15;
  const int batch = blockIdx.y;
  const int o0 = blockIdx.x * BM;

  if (MODE == 0 && flags && !flags[batch]) return;

  int idreg = 0;
  if (MODE == 1 && lane < TOPK_) idreg = idxp[batch * TOPK_ + lane];

  f32x4 acc[4][4] = {};

  auto issue = [&](int k0, int buf) {
    // A: wave w stages k-quads 4w..4w+3; each load = contiguous 1KB of
    // W'[kq][O][8] starting at output-row o0 (lane*16B appended by HW).
#pragma unroll
    for (int i = 0; i < 4; ++i) {
      int qk = w * 4 + i;
      const unsigned short* ga =
          Wb + (size_t)((k0 >> 3) + qk) * (O * 8) + (size_t)(o0 + lane) * 8;
      __builtin_amdgcn_global_load_lds((const AS1 void*)ga,
                                       (AS3 void*)(&Al[buf][qk * 512]), 16, 0, 0);
    }
    const unsigned short* base;
    if (MODE == 1) {
      int id = __shfl(idreg, k0 >> 8, 64);
      base = Xb + (size_t)id * (HW_ * RF_) + (size_t)((k0 & 255) >> 3) * 1024;
    } else {
      base = Xb + (size_t)batch * HW_ * K + (size_t)(k0 >> 3) * 1024;
    }
    // B: wave w stages 8 of 16 (qk, half) 1KB regions of X'[kq][s][8].
#pragma unroll
    for (int i = 0; i < 8; ++i) {
      int v = w * 8 + i;
      int qk = v >> 1, h = v & 1;
      const unsigned short* gb = base + (size_t)qk * 1024 + (size_t)(h * 64 + lane) * 8;
      __builtin_amdgcn_global_load_lds((const AS1 void*)gb,
                                       (AS3 void*)(&Bl[buf][qk * 1024 + h * 512]), 16, 0, 0);
    }
  };

  const int nIter = K / BKK;   // 32 (MODE 0/2/3) or 40 (MODE 1)

  issue(0, 0);
  issue(BKK, 1);               // 24 loads/wave outstanding

  for (int it = 0; it < nIter; ++it) {
    const int buf = it % 3;
    // Counted wait: stage-it loads (oldest 12) landed; stage-(it+1) loads
    // stay in flight across the barrier. Full drain only on the last iter.
    if (it + 1 < nIter) {
      asm volatile("s_waitcnt vmcnt(12)" ::: "memory");
    } else {
      asm volatile("s_waitcnt vmcnt(0)" ::: "memory");
    }
    __builtin_amdgcn_s_barrier();
#pragma unroll
    for (int s = 0; s < 2; ++s) {
      bf16x8 af[4], bfr[4];
#pragma unroll
      for (int mt = 0; mt < 4; ++mt)
        af[mt] = *(const bf16x8*)(&Al[buf][(s * 4 + q) * 512 + (mt * 16 + l15) * 8]);
#pragma unroll
      for (int nt = 0; nt < 4; ++nt)
        bfr[nt] = *(const bf16x8*)(&Bl[buf][(s * 4 + q) * 1024 + (w * 64 + nt * 16 + l15) * 8]);
#pragma unroll
      for (int mt = 0; mt < 4; ++mt)
#pragma unroll
        for (int nt = 0; nt < 4; ++nt)
          acc[mt][nt] = __builtin_amdgcn_mfma_f32_16x16x32_bf16(af[mt], bfr[nt], acc[mt][nt], 0, 0, 0);
    }
    if (it + 2 < nIter) issue((it + 2) * BKK, (it + 2) % 3);
  }

  // ---------------- epilogue ----------------
  const float CAL = 1.0f - 1.0f / 262144.0f;

  // MODE2 scratch aliases Al buffer 0 (safe: last K-stage uses buffer 1).
  float* nsumS = (float*)&Al[0][0];         // [2][64]
  float* nsqS  = (float*)&Al[0][0] + 128;   // [2][64]

  if (MODE == 2) {
#pragma unroll
    for (int mt = 0; mt < 4; ++mt)
#pragma unroll
      for (int reg = 0; reg < 4; ++reg) {
        float s_ = 0.f, q_ = 0.f;
#pragma unroll
        for (int nt = 0; nt < 4; ++nt) {
          float v = acc[mt][nt][reg];
          s_ += v; q_ += v * v;
        }
#pragma unroll
        for (int m = 1; m < 16; m <<= 1) {
          s_ += __shfl_xor(s_, m, 64);
          q_ += __shfl_xor(q_, m, 64);
        }
        if (l15 == 0) {
          int ol = mt * 16 + q * 4 + reg;
          nsumS[w * 64 + ol] = s_; nsqS[w * 64 + ol] = q_;
        }
      }
    __syncthreads();
  }

  if (MODE == 3) {
    float* ofb = (float*)OutP + (size_t)batch * DIM_ * HW_;
    const float* inb = inputs + (size_t)batch * DIM_ * HW_;
#pragma unroll
    for (int mt = 0; mt < 4; ++mt)
#pragma unroll
      for (int nt = 0; nt < 4; ++nt) {
        int o = o0 + mt * 16 + q * 4;
        int s = w * 64 + nt * 16 + l15;
        f32x4 v = acc[mt][nt];
#pragma unroll
        for (int g = 0; g < 4; ++g) {
          float in = inb[(size_t)(o + g) * HW_ + s];
          float sg = 1.f / (1.f + expf(-v[g]));
          ofb[(size_t)(o + g) * HW_ + s] = in * (1.f + sg);
        }
      }
  } else {
    // Store to X'[batch][o/8][s][8] (k-quad-major): ushort4 at
    // (o>>3)*1024 + s*8 + (o&7); (o&7) in {0,4}. Contiguous 256B per
    // 16-lane group instead of a 64-line scatter.
    unsigned short* ob = (unsigned short*)OutP + (size_t)batch * HW_ * Ldim;
    const float* inb = (MODE == 1) ? inputs + (size_t)batch * DIM_ * HW_ : nullptr;
#pragma unroll
    for (int mt = 0; mt < 4; ++mt) {
      float mean[4], rs[4];
      if (MODE == 2) {
#pragma unroll
        for (int reg = 0; reg < 4; ++reg) {
          int ol = mt * 16 + q * 4 + reg;
          float ts = nsumS[ol] + nsumS[64 + ol];
          float tq = nsqS[ol] + nsqS[64 + ol];
          float mn = ts * (1.f / 128.f);
          float vr = tq * (1.f / 128.f) - mn * mn;
          mean[reg] = mn; rs[reg] = rsqrtf(vr + 1e-5f);
        }
      }
#pragma unroll
      for (int nt = 0; nt < 4; ++nt) {
        int o = o0 + mt * 16 + q * 4;
        int s = w * 64 + nt * 16 + l15;
        f32x4 v = acc[mt][nt];
        float r[4];
        if (MODE == 0) {
#pragma unroll
          for (int g = 0; g < 4; ++g) r[g] = v[g];
        } else if (MODE == 1) {
          const float* ip = inb + (size_t)o * HW_ + s;
#pragma unroll
          for (int g = 0; g < 4; ++g)
            r[g] = fmaxf(0.f, 0.5f * ip[(size_t)g * HW_] + CAL * v[g]);
        } else {
#pragma unroll
          for (int g = 0; g < 4; ++g) r[g] = (v[g] - mean[g]) * rs[g];
        }
        ushort4 pk;
        pk.x = f2bf(r[0]); pk.y = f2bf(r[1]); pk.z = f2bf(r[2]); pk.w = f2bf(r[3]);
        *(ushort4*)(ob + (size_t)(o >> 3) * 1024 + (size_t)s * 8 + (o & 7)) = pk;
      }
    }
  }
}

// ---------------------------------------------------------------------------
extern "C" void kernel_launch(void* const* d_in, const int* in_sizes, int n_in,
                              void* d_out, int out_size, void* d_ws, size_t ws_size,
                              hipStream_t stream) {
  const float* inputs = (const float*)d_in[0];
  const float* proto  = (const float*)d_in[1];
  const float* w_rf   = (const float*)d_in[2];
  const float* w_rfmv = (const float*)d_in[3];
  const float* w_rms  = (const float*)d_in[4];
  const float* w_fuse = (const float*)d_in[5];
  float* out = (float*)d_out;

  uint8_t* ws = (uint8_t*)d_ws;
  size_t off = 0;
  auto alloc = [&](size_t bytes) { uint8_t* p = ws + off; off += (bytes + 255) & ~(size_t)255; return p; };

  float* dsum  = (float*)alloc(1088 * 4);       // 4352 B (256-aligned size)
  int*   flags = (int*)alloc(PN_ * 4);          // contiguous after dsum -> zeroed together
  int*   idx   = (int*)alloc(N_ * TOPK_ * 4);
  float* pnorm = (float*)alloc((size_t)(DIM_ / 32) * PN_ * 4);   // 64x64 partials
  unsigned short* wrf_b   = (unsigned short*)alloc((size_t)RF_ * DIM_ * 2);
  unsigned short* wrfmv_b = (unsigned short*)alloc((size_t)DIM_ * KMV * 2);
  unsigned short* wrms_b  = (unsigned short*)alloc((size_t)DIM_ * DIM_ * 2);
  unsigned short* wfuse_b = (unsigned short*)alloc((size_t)DIM_ * DIM_ * 2);
  unsigned short* xpT     = (unsigned short*)alloc((size_t)PN_ * HW_ * RF_ * 2);
  unsigned short* protoT  = (unsigned short*)alloc((size_t)PN_ * HW_ * DIM_ * 2);
  unsigned short* mvlT = protoT;                 // aliases (protoT dead after G1)
  unsigned short* mvaT = protoT + (size_t)N_ * HW_ * DIM_;

  cvt_all_kernel<<<864, 256, 0, stream>>>(w_rf, w_rfmv, w_rms, w_fuse,
                                          wrf_b, wrfmv_b, wrms_b, wfuse_b, dsum);
  transpose_proto_kernel<<<dim3(PN_, DIM_ / 32), 256, 0, stream>>>(proto, protoT, pnorm);
  dist_partial_kernel<<<512, 256, 0, stream>>>(inputs, proto, dsum);
  select_kernel<<<N_, 64, 0, stream>>>(dsum, pnorm, idx, flags);

  mfma_gemm_kernel<0><<<dim3(RF_ / BM, PN_), 128, 0, stream>>>(
      wrf_b, protoT, xpT, nullptr, nullptr, flags, DIM_, RF_, RF_);
  mfma_gemm_kernel<1><<<dim3(DIM_ / BM, N_), 128, 0, stream>>>(
      wrfmv_b, xpT, mvlT, inputs, idx, nullptr, KMV, DIM_, DIM_);
  mfma_gemm_kernel<2><<<dim3(DIM_ / BM, N_), 128, 0, stream>>>(
      wrms_b, mvlT, mvaT, nullptr, nullptr, nullptr, DIM_, DIM_, DIM_);
  mfma_gemm_kernel<3><<<dim3(DIM_ / BM, N_), 128, 0, stream>>>(
      wfuse_b, mvaT, out, inputs, nullptr, nullptr, DIM_, DIM_, DIM_);
}